// Round 1
// baseline (1174.942 us; speedup 1.0000x reference)
//
#include <hip/hip_runtime.h>
#include <hip/hip_bf16.h>
#include <cstddef>

// ---------------------------------------------------------------------------
// 2-layer GCN: out = A_norm(relu(A_norm(x@W1)+b1) @ W2) + b2
// A_norm = D^-1/2 (A+I) D^-1/2, self loops handled analytically.
// Strategy: per-call CSR build (hist -> scan -> scatter), then atomic-free
// per-node gather aggregation. fp32 throughout.
// ---------------------------------------------------------------------------

#define IN_F 512
#define HID 128
#define NCLS 32

// ---------------- degree histogram ----------------
__global__ void k_hist(const int* __restrict__ dst, int* __restrict__ deg, int E) {
    int e = blockIdx.x * 256 + threadIdx.x;
    if (e < E) atomicAdd(&deg[dst[e]], 1);
}

// ---------------- dinv = rsqrt(deg+1) ----------------
__global__ void k_dinv(const int* __restrict__ deg, float* __restrict__ dinv, int n) {
    int i = blockIdx.x * 256 + threadIdx.x;
    if (i < n) dinv[i] = rsqrtf((float)deg[i] + 1.0f);
}

// ---------------- 2-level exclusive scan (2048/block) ----------------
__global__ __launch_bounds__(256) void k_scan1(const int* __restrict__ deg, int* __restrict__ rs,
                                               int* __restrict__ bsum, int n) {
    __shared__ int sd[256];
    int base = blockIdx.x * 2048 + threadIdx.x * 8;
    int v[8];
    int t = 0;
#pragma unroll
    for (int i = 0; i < 8; ++i) {
        int x = (base + i < n) ? deg[base + i] : 0;
        v[i] = t;
        t += x;
    }
    sd[threadIdx.x] = t;
    __syncthreads();
    for (int off = 1; off < 256; off <<= 1) {
        int x = 0;
        if ((int)threadIdx.x >= off) x = sd[threadIdx.x - off];
        __syncthreads();
        if ((int)threadIdx.x >= off) sd[threadIdx.x] += x;
        __syncthreads();
    }
    int texcl = sd[threadIdx.x] - t;
#pragma unroll
    for (int i = 0; i < 8; ++i)
        if (base + i < n) rs[base + i] = texcl + v[i];
    if (threadIdx.x == 255) bsum[blockIdx.x] = sd[255];
}

__global__ void k_scan2(int* bsum, int nb) {
    if (threadIdx.x == 0 && blockIdx.x == 0) {
        int run = 0;
        for (int b = 0; b < nb; ++b) { int t = bsum[b]; bsum[b] = run; run += t; }
    }
}

__global__ void k_scan3(int* __restrict__ rs, const int* __restrict__ bsum,
                        int* __restrict__ cursor, int n) {
    int i = blockIdx.x * 256 + threadIdx.x;
    if (i < n) {
        int r = rs[i] + bsum[i >> 11];
        rs[i] = r;
        cursor[i] = r;
    }
}

// ---------------- scatter edges into CSR ----------------
__global__ void k_scatter(const int* __restrict__ src, const int* __restrict__ dst,
                          int* cursor, int* __restrict__ csr, int E) {
    int e = blockIdx.x * 256 + threadIdx.x;
    if (e < E) {
        int d = dst[e];
        int pos = atomicAdd(&cursor[d], 1);
        csr[pos] = src[e];
    }
}

// ---------------- GEMM1: [M,512] x [512,128] -> [M,128], fp32 tiled ----------------
#define BM 64
#define BN 128
#define BK 32
__global__ __launch_bounds__(256) void k_gemm1(const float* __restrict__ A, const float* __restrict__ B,
                                               float* __restrict__ C, int M) {
    __shared__ float As[BK][BM + 1];  // [32][65]
    __shared__ float Bs[BK][BN];      // [32][128]
    const int tid = threadIdx.x;
    const int tx = tid & 31;  // col group
    const int ty = tid >> 5;  // row group 0..7
    const int rowBase = blockIdx.x * BM;
    float acc[8][4];
#pragma unroll
    for (int i = 0; i < 8; ++i)
#pragma unroll
        for (int j = 0; j < 4; ++j) acc[i][j] = 0.f;

    for (int k0 = 0; k0 < IN_F; k0 += BK) {
#pragma unroll
        for (int it = 0; it < 8; ++it) {   // A tile 64x32
            int idx = tid + 256 * it;
            int r = idx >> 5;
            int kk = idx & 31;
            int gr = rowBase + r;
            As[kk][r] = (gr < M) ? A[(size_t)gr * IN_F + k0 + kk] : 0.f;
        }
#pragma unroll
        for (int it = 0; it < 16; ++it) {  // B tile 32x128
            int idx = tid + 256 * it;
            int kk = idx >> 7;
            int c = idx & 127;
            Bs[kk][c] = B[(size_t)(k0 + kk) * BN + c];
        }
        __syncthreads();
#pragma unroll
        for (int kk = 0; kk < BK; ++kk) {
            float b[4], a[8];
#pragma unroll
            for (int j = 0; j < 4; ++j) b[j] = Bs[kk][tx + 32 * j];
#pragma unroll
            for (int i = 0; i < 8; ++i) a[i] = As[kk][ty * 8 + i];
#pragma unroll
            for (int i = 0; i < 8; ++i)
#pragma unroll
                for (int j = 0; j < 4; ++j) acc[i][j] += a[i] * b[j];
        }
        __syncthreads();
    }
#pragma unroll
    for (int i = 0; i < 8; ++i) {
        int gr = rowBase + ty * 8 + i;
        if (gr < M) {
#pragma unroll
            for (int j = 0; j < 4; ++j) C[(size_t)gr * HID + tx + 32 * j] = acc[i][j];
        }
    }
}

// ---------------- agg layer1: one wave per node, 128 feats = float2/lane ----------------
__global__ __launch_bounds__(256) void k_agg1(const float* __restrict__ h, const int* __restrict__ csr,
                                              const int* __restrict__ rs, const int* __restrict__ cnt,
                                              const float* __restrict__ dinv, const float* __restrict__ b1,
                                              float* __restrict__ h1, int N) {
    int v = blockIdx.x * 4 + (threadIdx.x >> 6);
    if (v >= N) return;
    int lane = threadIdx.x & 63;
    float dv = dinv[v];
    const float2* hv = (const float2*)(h + (size_t)v * HID) + lane;
    float2 a0 = *hv;
    float2 acc;
    acc.x = a0.x * dv * dv;  // self loop
    acc.y = a0.y * dv * dv;
    int start = rs[v];
    int c = cnt[v];
    for (int i = 0; i < c; ++i) {
        int s = csr[start + i];
        float ns = dinv[s] * dv;
        float2 hs = *((const float2*)(h + (size_t)s * HID) + lane);
        acc.x += hs.x * ns;
        acc.y += hs.y * ns;
    }
    float2 bb = *((const float2*)b1 + lane);
    float ox = acc.x + bb.x, oy = acc.y + bb.y;
    ox = ox > 0.f ? ox : 0.f;
    oy = oy > 0.f ? oy : 0.f;
    float2 o;
    o.x = ox; o.y = oy;
    *((float2*)(h1 + (size_t)v * HID) + lane) = o;
}

// ---------------- GEMM2: [M,128] x [128,32] -> [M,32] ----------------
__global__ __launch_bounds__(256) void k_gemm2(const float* __restrict__ A, const float* __restrict__ B,
                                               float* __restrict__ C, int M) {
    __shared__ float Bs[HID][NCLS];   // 16 KB
    __shared__ float As[64][HID];     // 32 KB
    const int tid = threadIdx.x;
#pragma unroll
    for (int it = 0; it < 16; ++it) {  // 128*32/256
        int idx = tid + 256 * it;
        Bs[idx >> 5][idx & 31] = B[idx];
    }
    int rowBase = blockIdx.x * 64;
#pragma unroll
    for (int it = 0; it < 32; ++it) {  // 64*128/256
        int idx = tid + 256 * it;
        int r = idx >> 7, cc = idx & 127;
        int gr = rowBase + r;
        As[r][cc] = (gr < M) ? A[(size_t)gr * HID + cc] : 0.f;
    }
    __syncthreads();
    int col = tid & 31;
    int rg = tid >> 5;  // 0..7
    float acc[8];
#pragma unroll
    for (int i = 0; i < 8; ++i) acc[i] = 0.f;
    for (int k = 0; k < HID; ++k) {
        float b = Bs[k][col];
#pragma unroll
        for (int i = 0; i < 8; ++i) acc[i] += As[rg * 8 + i][k] * b;
    }
#pragma unroll
    for (int i = 0; i < 8; ++i) {
        int gr = rowBase + rg * 8 + i;
        if (gr < M) C[(size_t)gr * NCLS + col] = acc[i];
    }
}

// ---------------- agg layer2: one wave per node, 32 feats, 2 edges in flight ----------------
__global__ __launch_bounds__(256) void k_agg2(const float* __restrict__ h2, const int* __restrict__ csr,
                                              const int* __restrict__ rs, const int* __restrict__ cnt,
                                              const float* __restrict__ dinv, const float* __restrict__ b2,
                                              float* __restrict__ out, int N) {
    int v = blockIdx.x * 4 + (threadIdx.x >> 6);
    if (v >= N) return;
    int lane = threadIdx.x & 63;
    int f = lane & 31;
    int half = lane >> 5;
    float dv = dinv[v];
    float acc = 0.f;
    if (half == 0) acc = h2[(size_t)v * NCLS + f] * dv * dv;  // self loop
    int start = rs[v];
    int c = cnt[v];
    for (int i = half; i < c; i += 2) {
        int s = csr[start + i];
        acc += h2[(size_t)s * NCLS + f] * (dinv[s] * dv);
    }
    acc += __shfl_xor(acc, 32, 64);
    if (half == 0) out[(size_t)v * NCLS + f] = acc + b2[f];
}

// ---------------------------------------------------------------------------
extern "C" void kernel_launch(void* const* d_in, const int* in_sizes, int n_in,
                              void* d_out, int out_size, void* d_ws, size_t ws_size,
                              hipStream_t stream) {
    const float* x = (const float*)d_in[0];
    const int* edge_index = (const int*)d_in[1];
    const float* W1 = (const float*)d_in[2];
    const float* b1 = (const float*)d_in[3];
    const float* W2 = (const float*)d_in[4];
    const float* b2 = (const float*)d_in[5];
    float* out = (float*)d_out;

    const int N = in_sizes[0] / IN_F;       // 100000
    const int E = in_sizes[1] / 2;          // 1600000
    const int* e_src = edge_index;
    const int* e_dst = edge_index + E;

    // workspace carve-up (256B aligned)
    char* ws = (char*)d_ws;
    size_t off = 0;
    auto alloc = [&](size_t bytes) -> char* {
        char* p = ws + off;
        off += (bytes + 255) & ~(size_t)255;
        return p;
    };
    int* deg      = (int*)alloc((size_t)N * 4);
    float* dinv   = (float*)alloc((size_t)N * 4);
    int* rs       = (int*)alloc((size_t)N * 4);
    int* cursor   = (int*)alloc((size_t)N * 4);
    int* bsum     = (int*)alloc(1024 * 4);
    int* csr      = (int*)alloc((size_t)E * 4);
    float* h      = (float*)alloc((size_t)N * HID * 4);  // reused as h2 (N*NCLS)
    float* h1     = (float*)alloc((size_t)N * HID * 4);
    float* h2     = h;  // reuse: h dead after agg1

    const int nbE = (E + 255) / 256;
    const int nbN = (N + 255) / 256;
    const int nbScan = (N + 2047) / 2048;
    const int nbNode = (N + 3) / 4;

    hipMemsetAsync(deg, 0, (size_t)N * 4, stream);
    k_hist<<<nbE, 256, 0, stream>>>(e_dst, deg, E);
    k_dinv<<<nbN, 256, 0, stream>>>(deg, dinv, N);
    k_scan1<<<nbScan, 256, 0, stream>>>(deg, rs, bsum, N);
    k_scan2<<<1, 64, 0, stream>>>(bsum, nbScan);
    k_scan3<<<nbN, 256, 0, stream>>>(rs, bsum, cursor, N);
    k_scatter<<<nbE, 256, 0, stream>>>(e_src, e_dst, cursor, csr, E);

    k_gemm1<<<(N + BM - 1) / BM, 256, 0, stream>>>(x, W1, h, N);
    k_agg1<<<nbNode, 256, 0, stream>>>(h, csr, rs, deg, dinv, b1, h1, N);
    k_gemm2<<<(N + 63) / 64, 256, 0, stream>>>(h1, W2, h2, N);
    k_agg2<<<nbNode, 256, 0, stream>>>(h2, csr, rs, deg, dinv, b2, out, N);
}

// Round 2
// 814.532 us; speedup vs baseline: 1.4425x; 1.4425x over previous
//
#include <hip/hip_runtime.h>
#include <hip/hip_bf16.h>
#include <cstddef>

// ---------------------------------------------------------------------------
// 2-layer GCN: out = A_norm(relu(A_norm(x@W1)+b1) @ W2) + b2
// R2: GEMM1 via bf16 MFMA (fp32->bf16 fused into LDS staging), h/h1 stored
// bf16 to halve aggregation gather traffic. CSR build per call (hist->scan->
// scatter), atomic-free per-node gather aggregation, fp32 accumulation.
// ---------------------------------------------------------------------------

#define IN_F 512
#define HID 128
#define NCLS 32

typedef __attribute__((ext_vector_type(8))) short bf16x8;
typedef __attribute__((ext_vector_type(4))) float f32x4;

__device__ __forceinline__ unsigned short f2bf(float f) {
    union { float f; unsigned u; } v; v.f = f;
    unsigned r = v.u + 0x7fff + ((v.u >> 16) & 1);   // RNE
    return (unsigned short)(r >> 16);
}
__device__ __forceinline__ float bf2f(unsigned short h) {
    union { unsigned u; float f; } v; v.u = ((unsigned)h) << 16;
    return v.f;
}

// ---------------- degree histogram ----------------
__global__ void k_hist(const int* __restrict__ dst, int* __restrict__ deg, int E) {
    int e = blockIdx.x * 256 + threadIdx.x;
    if (e < E) atomicAdd(&deg[dst[e]], 1);
}

// ---------------- dinv = rsqrt(deg+1) ----------------
__global__ void k_dinv(const int* __restrict__ deg, float* __restrict__ dinv, int n) {
    int i = blockIdx.x * 256 + threadIdx.x;
    if (i < n) dinv[i] = rsqrtf((float)deg[i] + 1.0f);
}

// ---------------- W1 [512][128] fp32 -> W1T [128][512] bf16 bits ----------------
__global__ void k_prep(const float* __restrict__ W1, unsigned short* __restrict__ W1T) {
    int i = blockIdx.x * 256 + threadIdx.x;   // 65536 total
    int n = i >> 9, k = i & 511;
    W1T[(size_t)n * IN_F + k] = f2bf(W1[(size_t)k * HID + n]);
}

// ---------------- 2-level exclusive scan (2048/block) ----------------
__global__ __launch_bounds__(256) void k_scan1(const int* __restrict__ deg, int* __restrict__ rs,
                                               int* __restrict__ bsum, int n) {
    __shared__ int sd[256];
    int base = blockIdx.x * 2048 + threadIdx.x * 8;
    int v[8];
    int t = 0;
#pragma unroll
    for (int i = 0; i < 8; ++i) {
        int x = (base + i < n) ? deg[base + i] : 0;
        v[i] = t;
        t += x;
    }
    sd[threadIdx.x] = t;
    __syncthreads();
    for (int off = 1; off < 256; off <<= 1) {
        int x = 0;
        if ((int)threadIdx.x >= off) x = sd[threadIdx.x - off];
        __syncthreads();
        if ((int)threadIdx.x >= off) sd[threadIdx.x] += x;
        __syncthreads();
    }
    int texcl = sd[threadIdx.x] - t;
#pragma unroll
    for (int i = 0; i < 8; ++i)
        if (base + i < n) rs[base + i] = texcl + v[i];
    if (threadIdx.x == 255) bsum[blockIdx.x] = sd[255];
}

__global__ void k_scan2(int* bsum, int nb) {
    if (threadIdx.x == 0 && blockIdx.x == 0) {
        int run = 0;
        for (int b = 0; b < nb; ++b) { int t = bsum[b]; bsum[b] = run; run += t; }
    }
}

__global__ void k_scan3(int* __restrict__ rs, const int* __restrict__ bsum,
                        int* __restrict__ cursor, int n) {
    int i = blockIdx.x * 256 + threadIdx.x;
    if (i < n) {
        int r = rs[i] + bsum[i >> 11];
        rs[i] = r;
        cursor[i] = r;
    }
}

// ---------------- scatter edges into CSR ----------------
__global__ void k_scatter(const int* __restrict__ src, const int* __restrict__ dst,
                          int* cursor, int* __restrict__ csr, int E) {
    int e = blockIdx.x * 256 + threadIdx.x;
    if (e < E) {
        int d = dst[e];
        int pos = atomicAdd(&cursor[d], 1);
        csr[pos] = src[e];
    }
}

// ---------------- GEMM1: x[M,512]fp32 @ W1T[128,512]bf16 -> h[M,128]bf16, MFMA ----------------
// 128x128 block tile, 4 waves, each wave 32 rows x 128 cols = 2x8 mfma tiles.
#define LSTR 40   // LDS row stride in bf16 elems (80B): keeps ds_read_b128 16B-aligned, 2-way banks (free)
__global__ __launch_bounds__(256) void k_gemm1(const float* __restrict__ A,
                                               const unsigned short* __restrict__ BT,
                                               unsigned short* __restrict__ C, int M) {
    __shared__ unsigned short As[128 * LSTR];
    __shared__ unsigned short Bs[128 * LSTR];
    const int tid = threadIdx.x;
    const int wave = tid >> 6;
    const int lane = tid & 63;
    const int l16 = lane & 15;
    const int q = lane >> 4;
    const int rowBase = blockIdx.x * 128;

    f32x4 acc[2][8];
#pragma unroll
    for (int mt = 0; mt < 2; ++mt)
#pragma unroll
        for (int nt = 0; nt < 8; ++nt) acc[mt][nt] = (f32x4){0.f, 0.f, 0.f, 0.f};

    for (int k0 = 0; k0 < IN_F; k0 += 32) {
        // stage A: 128 rows x 32 k (fp32 -> bf16). 1024 float4 chunks.
#pragma unroll
        for (int it = 0; it < 4; ++it) {
            int idx = tid + 256 * it;
            int r = idx >> 3;          // 0..127
            int kq = idx & 7;          // float4 chunk within 32
            int gr = rowBase + r;
            float4 v = make_float4(0.f, 0.f, 0.f, 0.f);
            if (gr < M) v = *(const float4*)(A + (size_t)gr * IN_F + k0 + kq * 4);
            short4 pk;
            pk.x = (short)f2bf(v.x); pk.y = (short)f2bf(v.y);
            pk.z = (short)f2bf(v.z); pk.w = (short)f2bf(v.w);
            *(short4*)(As + r * LSTR + kq * 4) = pk;
        }
        // stage B: 128 n-rows x 32 k from W1T (bf16, contiguous in k). 512 16B chunks.
#pragma unroll
        for (int it = 0; it < 2; ++it) {
            int idx = tid + 256 * it;
            int n = idx >> 2;          // 0..127
            int kc = idx & 3;          // 8-elem chunk
            uint4 v = *(const uint4*)(BT + (size_t)n * IN_F + k0 + kc * 8);
            *(uint4*)(Bs + n * LSTR + kc * 8) = v;
        }
        __syncthreads();

        bf16x8 a_frag[2], b_frag[8];
#pragma unroll
        for (int mt = 0; mt < 2; ++mt)
            a_frag[mt] = *(const bf16x8*)(As + (wave * 32 + mt * 16 + l16) * LSTR + q * 8);
#pragma unroll
        for (int nt = 0; nt < 8; ++nt)
            b_frag[nt] = *(const bf16x8*)(Bs + (nt * 16 + l16) * LSTR + q * 8);
#pragma unroll
        for (int mt = 0; mt < 2; ++mt)
#pragma unroll
            for (int nt = 0; nt < 8; ++nt)
                acc[mt][nt] = __builtin_amdgcn_mfma_f32_16x16x32_bf16(
                    a_frag[mt], b_frag[nt], acc[mt][nt], 0, 0, 0);
        __syncthreads();
    }

    // epilogue: C/D layout col=lane&15, row=(lane>>4)*4+r
#pragma unroll
    for (int mt = 0; mt < 2; ++mt) {
#pragma unroll
        for (int r = 0; r < 4; ++r) {
            int row = rowBase + wave * 32 + mt * 16 + q * 4 + r;
            if (row < M) {
#pragma unroll
                for (int nt = 0; nt < 8; ++nt) {
                    int col = nt * 16 + l16;
                    C[(size_t)row * HID + col] = f2bf(acc[mt][nt][r]);
                }
            }
        }
    }
}

// ---------------- agg layer1: one wave per node, 128 bf16 feats = uint/lane ----------------
__global__ __launch_bounds__(256) void k_agg1(const unsigned short* __restrict__ h,
                                              const int* __restrict__ csr,
                                              const int* __restrict__ rs, const int* __restrict__ cnt,
                                              const float* __restrict__ dinv, const float* __restrict__ b1,
                                              unsigned short* __restrict__ h1, int N) {
    int v = blockIdx.x * 4 + (threadIdx.x >> 6);
    if (v >= N) return;
    int lane = threadIdx.x & 63;
    float dv = dinv[v];
    const unsigned* hrow = (const unsigned*)h;
    unsigned u = hrow[(size_t)v * 64 + lane];
    float ax = bf2f((unsigned short)(u & 0xffff)) * dv * dv;   // self loop
    float ay = bf2f((unsigned short)(u >> 16)) * dv * dv;
    int start = rs[v];
    int c = cnt[v];
    for (int i = 0; i < c; ++i) {
        int s = csr[start + i];
        float ns = dinv[s] * dv;
        unsigned us = hrow[(size_t)s * 64 + lane];
        ax += bf2f((unsigned short)(us & 0xffff)) * ns;
        ay += bf2f((unsigned short)(us >> 16)) * ns;
    }
    ax += b1[2 * lane];
    ay += b1[2 * lane + 1];
    ax = fmaxf(ax, 0.f);
    ay = fmaxf(ay, 0.f);
    ((unsigned*)h1)[(size_t)v * 64 + lane] =
        (unsigned)f2bf(ax) | ((unsigned)f2bf(ay) << 16);
}

// ---------------- GEMM2: h1[M,128]bf16 @ W2[128,32]fp32 -> h2[M,32]fp32 (VALU) ----------------
__global__ __launch_bounds__(256) void k_gemm2(const unsigned short* __restrict__ A,
                                               const float* __restrict__ B,
                                               float* __restrict__ C, int M) {
    __shared__ float Bs[HID][NCLS];   // 16 KB
    __shared__ float As[64][HID];     // 32 KB
    const int tid = threadIdx.x;
#pragma unroll
    for (int it = 0; it < 16; ++it) {  // 128*32/256
        int idx = tid + 256 * it;
        Bs[idx >> 5][idx & 31] = B[idx];
    }
    int rowBase = blockIdx.x * 64;
    const unsigned* A2 = (const unsigned*)A;
#pragma unroll
    for (int it = 0; it < 16; ++it) {  // 64*64 uint chunks
        int idx = tid + 256 * it;
        int r = idx >> 6, c2 = idx & 63;
        int gr = rowBase + r;
        unsigned u = (gr < M) ? A2[(size_t)gr * 64 + c2] : 0u;
        As[r][2 * c2]     = bf2f((unsigned short)(u & 0xffff));
        As[r][2 * c2 + 1] = bf2f((unsigned short)(u >> 16));
    }
    __syncthreads();
    int col = tid & 31;
    int rg = tid >> 5;  // 0..7
    float acc[8];
#pragma unroll
    for (int i = 0; i < 8; ++i) acc[i] = 0.f;
    for (int k = 0; k < HID; ++k) {
        float b = Bs[k][col];
#pragma unroll
        for (int i = 0; i < 8; ++i) acc[i] += As[rg * 8 + i][k] * b;
    }
#pragma unroll
    for (int i = 0; i < 8; ++i) {
        int gr = rowBase + rg * 8 + i;
        if (gr < M) C[(size_t)gr * NCLS + col] = acc[i];
    }
}

// ---------------- agg layer2: one wave per node, 32 feats, 2 edges in flight ----------------
__global__ __launch_bounds__(256) void k_agg2(const float* __restrict__ h2, const int* __restrict__ csr,
                                              const int* __restrict__ rs, const int* __restrict__ cnt,
                                              const float* __restrict__ dinv, const float* __restrict__ b2,
                                              float* __restrict__ out, int N) {
    int v = blockIdx.x * 4 + (threadIdx.x >> 6);
    if (v >= N) return;
    int lane = threadIdx.x & 63;
    int f = lane & 31;
    int half = lane >> 5;
    float dv = dinv[v];
    float acc = 0.f;
    if (half == 0) acc = h2[(size_t)v * NCLS + f] * dv * dv;  // self loop
    int start = rs[v];
    int c = cnt[v];
    for (int i = half; i < c; i += 2) {
        int s = csr[start + i];
        acc += h2[(size_t)s * NCLS + f] * (dinv[s] * dv);
    }
    acc += __shfl_xor(acc, 32, 64);
    if (half == 0) out[(size_t)v * NCLS + f] = acc + b2[f];
}

// ---------------------------------------------------------------------------
extern "C" void kernel_launch(void* const* d_in, const int* in_sizes, int n_in,
                              void* d_out, int out_size, void* d_ws, size_t ws_size,
                              hipStream_t stream) {
    const float* x = (const float*)d_in[0];
    const int* edge_index = (const int*)d_in[1];
    const float* W1 = (const float*)d_in[2];
    const float* b1 = (const float*)d_in[3];
    const float* W2 = (const float*)d_in[4];
    const float* b2 = (const float*)d_in[5];
    float* out = (float*)d_out;

    const int N = in_sizes[0] / IN_F;       // 100000
    const int E = in_sizes[1] / 2;          // 1600000
    const int* e_src = edge_index;
    const int* e_dst = edge_index + E;

    // workspace carve-up (256B aligned)
    char* ws = (char*)d_ws;
    size_t off = 0;
    auto alloc = [&](size_t bytes) -> char* {
        char* p = ws + off;
        off += (bytes + 255) & ~(size_t)255;
        return p;
    };
    int* deg             = (int*)alloc((size_t)N * 4);
    float* dinv          = (float*)alloc((size_t)N * 4);
    int* rs              = (int*)alloc((size_t)N * 4);
    int* cursor          = (int*)alloc((size_t)N * 4);
    int* bsum            = (int*)alloc(1024 * 4);
    int* csr             = (int*)alloc((size_t)E * 4);
    unsigned short* W1T  = (unsigned short*)alloc((size_t)HID * IN_F * 2);   // 128K
    unsigned short* h    = (unsigned short*)alloc((size_t)N * HID * 2);      // 25.6 MB, bf16
    unsigned short* h1   = (unsigned short*)alloc((size_t)N * HID * 2);      // 25.6 MB, bf16
    float* h2            = (float*)h;   // h dead after agg1; 12.8 MB fp32 fits in 25.6

    const int nbE = (E + 255) / 256;
    const int nbN = (N + 255) / 256;
    const int nbScan = (N + 2047) / 2048;
    const int nbNode = (N + 3) / 4;

    hipMemsetAsync(deg, 0, (size_t)N * 4, stream);
    k_hist<<<nbE, 256, 0, stream>>>(e_dst, deg, E);
    k_dinv<<<nbN, 256, 0, stream>>>(deg, dinv, N);
    k_scan1<<<nbScan, 256, 0, stream>>>(deg, rs, bsum, N);
    k_scan2<<<1, 64, 0, stream>>>(bsum, nbScan);
    k_scan3<<<nbN, 256, 0, stream>>>(rs, bsum, cursor, N);
    k_scatter<<<nbE, 256, 0, stream>>>(e_src, e_dst, cursor, csr, E);
    k_prep<<<(HID * IN_F) / 256, 256, 0, stream>>>(W1, W1T);

    k_gemm1<<<(N + 127) / 128, 256, 0, stream>>>(x, W1T, h, N);
    k_agg1<<<nbNode, 256, 0, stream>>>(h, csr, rs, deg, dinv, b1, h1, N);
    k_gemm2<<<(N + 63) / 64, 256, 0, stream>>>(h1, W2, h2, N);
    k_agg2<<<nbNode, 256, 0, stream>>>(h2, csr, rs, deg, dinv, b2, out, N);
}

// Round 3
// 697.634 us; speedup vs baseline: 1.6842x; 1.1676x over previous
//
#include <hip/hip_runtime.h>
#include <hip/hip_bf16.h>
#include <cstddef>

// ---------------------------------------------------------------------------
// 2-layer GCN: out = A_norm(relu(A_norm(x@W1)+b1) @ W2) + b2
// R3: pre-scale h by dinv in GEMM epilogues (removes dependent dinv[s] load
// from gather loops); unroll gather loops x8 for MLP. h/h1/h2 all bf16.
// ---------------------------------------------------------------------------

#define IN_F 512
#define HID 128
#define NCLS 32

typedef __attribute__((ext_vector_type(8))) short bf16x8;
typedef __attribute__((ext_vector_type(4))) float f32x4;

__device__ __forceinline__ unsigned short f2bf(float f) {
    union { float f; unsigned u; } v; v.f = f;
    unsigned r = v.u + 0x7fff + ((v.u >> 16) & 1);   // RNE
    return (unsigned short)(r >> 16);
}
__device__ __forceinline__ float bf2f(unsigned short h) {
    union { unsigned u; float f; } v; v.u = ((unsigned)h) << 16;
    return v.f;
}
__device__ __forceinline__ float lo16(unsigned u) { return bf2f((unsigned short)(u & 0xffff)); }
__device__ __forceinline__ float hi16(unsigned u) { return bf2f((unsigned short)(u >> 16)); }

// ---------------- degree histogram ----------------
__global__ void k_hist(const int* __restrict__ dst, int* __restrict__ deg, int E) {
    int e = blockIdx.x * 256 + threadIdx.x;
    if (e < E) atomicAdd(&deg[dst[e]], 1);
}

// ---------------- dinv = rsqrt(deg+1) ----------------
__global__ void k_dinv(const int* __restrict__ deg, float* __restrict__ dinv, int n) {
    int i = blockIdx.x * 256 + threadIdx.x;
    if (i < n) dinv[i] = rsqrtf((float)deg[i] + 1.0f);
}

// ---------------- W1 [512][128] fp32 -> W1T [128][512] bf16 bits ----------------
__global__ void k_prep(const float* __restrict__ W1, unsigned short* __restrict__ W1T) {
    int i = blockIdx.x * 256 + threadIdx.x;   // 65536 total
    int n = i >> 9, k = i & 511;
    W1T[(size_t)n * IN_F + k] = f2bf(W1[(size_t)k * HID + n]);
}

// ---------------- 2-level exclusive scan (2048/block) ----------------
__global__ __launch_bounds__(256) void k_scan1(const int* __restrict__ deg, int* __restrict__ rs,
                                               int* __restrict__ bsum, int n) {
    __shared__ int sd[256];
    int base = blockIdx.x * 2048 + threadIdx.x * 8;
    int v[8];
    int t = 0;
#pragma unroll
    for (int i = 0; i < 8; ++i) {
        int x = (base + i < n) ? deg[base + i] : 0;
        v[i] = t;
        t += x;
    }
    sd[threadIdx.x] = t;
    __syncthreads();
    for (int off = 1; off < 256; off <<= 1) {
        int x = 0;
        if ((int)threadIdx.x >= off) x = sd[threadIdx.x - off];
        __syncthreads();
        if ((int)threadIdx.x >= off) sd[threadIdx.x] += x;
        __syncthreads();
    }
    int texcl = sd[threadIdx.x] - t;
#pragma unroll
    for (int i = 0; i < 8; ++i)
        if (base + i < n) rs[base + i] = texcl + v[i];
    if (threadIdx.x == 255) bsum[blockIdx.x] = sd[255];
}

__global__ void k_scan2(int* bsum, int nb) {
    if (threadIdx.x == 0 && blockIdx.x == 0) {
        int run = 0;
        for (int b = 0; b < nb; ++b) { int t = bsum[b]; bsum[b] = run; run += t; }
    }
}

__global__ void k_scan3(int* __restrict__ rs, const int* __restrict__ bsum,
                        int* __restrict__ cursor, int n) {
    int i = blockIdx.x * 256 + threadIdx.x;
    if (i < n) {
        int r = rs[i] + bsum[i >> 11];
        rs[i] = r;
        cursor[i] = r;
    }
}

// ---------------- scatter edges into CSR ----------------
__global__ void k_scatter(const int* __restrict__ src, const int* __restrict__ dst,
                          int* cursor, int* __restrict__ csr, int E) {
    int e = blockIdx.x * 256 + threadIdx.x;
    if (e < E) {
        int d = dst[e];
        int pos = atomicAdd(&cursor[d], 1);
        csr[pos] = src[e];
    }
}

// ---------------- GEMM1: x[M,512]fp32 @ W1T[128,512]bf16 -> hs[M,128]bf16 (pre-scaled by dinv) ----
#define LSTR 40   // LDS row stride in bf16 elems (80B)
__global__ __launch_bounds__(256) void k_gemm1(const float* __restrict__ A,
                                               const unsigned short* __restrict__ BT,
                                               const float* __restrict__ dinv,
                                               unsigned short* __restrict__ C, int M) {
    __shared__ unsigned short As[128 * LSTR];
    __shared__ unsigned short Bs[128 * LSTR];
    const int tid = threadIdx.x;
    const int wave = tid >> 6;
    const int lane = tid & 63;
    const int l16 = lane & 15;
    const int q = lane >> 4;
    const int rowBase = blockIdx.x * 128;

    f32x4 acc[2][8];
#pragma unroll
    for (int mt = 0; mt < 2; ++mt)
#pragma unroll
        for (int nt = 0; nt < 8; ++nt) acc[mt][nt] = (f32x4){0.f, 0.f, 0.f, 0.f};

    for (int k0 = 0; k0 < IN_F; k0 += 32) {
#pragma unroll
        for (int it = 0; it < 4; ++it) {
            int idx = tid + 256 * it;
            int r = idx >> 3;
            int kq = idx & 7;
            int gr = rowBase + r;
            float4 v = make_float4(0.f, 0.f, 0.f, 0.f);
            if (gr < M) v = *(const float4*)(A + (size_t)gr * IN_F + k0 + kq * 4);
            short4 pk;
            pk.x = (short)f2bf(v.x); pk.y = (short)f2bf(v.y);
            pk.z = (short)f2bf(v.z); pk.w = (short)f2bf(v.w);
            *(short4*)(As + r * LSTR + kq * 4) = pk;
        }
#pragma unroll
        for (int it = 0; it < 2; ++it) {
            int idx = tid + 256 * it;
            int n = idx >> 2;
            int kc = idx & 3;
            uint4 v = *(const uint4*)(BT + (size_t)n * IN_F + k0 + kc * 8);
            *(uint4*)(Bs + n * LSTR + kc * 8) = v;
        }
        __syncthreads();

        bf16x8 a_frag[2], b_frag[8];
#pragma unroll
        for (int mt = 0; mt < 2; ++mt)
            a_frag[mt] = *(const bf16x8*)(As + (wave * 32 + mt * 16 + l16) * LSTR + q * 8);
#pragma unroll
        for (int nt = 0; nt < 8; ++nt)
            b_frag[nt] = *(const bf16x8*)(Bs + (nt * 16 + l16) * LSTR + q * 8);
#pragma unroll
        for (int mt = 0; mt < 2; ++mt)
#pragma unroll
            for (int nt = 0; nt < 8; ++nt)
                acc[mt][nt] = __builtin_amdgcn_mfma_f32_16x16x32_bf16(
                    a_frag[mt], b_frag[nt], acc[mt][nt], 0, 0, 0);
        __syncthreads();
    }

    // epilogue: C/D layout col=lane&15, row=(lane>>4)*4+r; fuse dinv[row] scale
#pragma unroll
    for (int mt = 0; mt < 2; ++mt) {
#pragma unroll
        for (int r = 0; r < 4; ++r) {
            int row = rowBase + wave * 32 + mt * 16 + q * 4 + r;
            if (row < M) {
                float sc = dinv[row];
#pragma unroll
                for (int nt = 0; nt < 8; ++nt) {
                    int col = nt * 16 + l16;
                    C[(size_t)row * HID + col] = f2bf(acc[mt][nt][r] * sc);
                }
            }
        }
    }
}

// ---------------- agg layer1: out[v]=relu(dv*(sum hs[nbr]+hs[v])+b1), unroll x8 ----------------
__global__ __launch_bounds__(256) void k_agg1(const unsigned short* __restrict__ hs,
                                              const int* __restrict__ csr,
                                              const int* __restrict__ rs, const int* __restrict__ cnt,
                                              const float* __restrict__ dinv, const float* __restrict__ b1,
                                              unsigned short* __restrict__ h1, int N) {
    int v = blockIdx.x * 4 + (threadIdx.x >> 6);
    if (v >= N) return;
    int lane = threadIdx.x & 63;
    float dv = dinv[v];
    const unsigned* hrow = (const unsigned*)hs;
    unsigned u = hrow[(size_t)v * 64 + lane];   // self (pre-scaled)
    float ax = lo16(u), ay = hi16(u);
    int start = rs[v];
    int c = cnt[v];
    int i = 0;
    for (; i + 8 <= c; i += 8) {
        int s0 = csr[start + i + 0], s1 = csr[start + i + 1];
        int s2 = csr[start + i + 2], s3 = csr[start + i + 3];
        int s4 = csr[start + i + 4], s5 = csr[start + i + 5];
        int s6 = csr[start + i + 6], s7 = csr[start + i + 7];
        unsigned u0 = hrow[(size_t)s0 * 64 + lane];
        unsigned u1 = hrow[(size_t)s1 * 64 + lane];
        unsigned u2 = hrow[(size_t)s2 * 64 + lane];
        unsigned u3 = hrow[(size_t)s3 * 64 + lane];
        unsigned u4 = hrow[(size_t)s4 * 64 + lane];
        unsigned u5 = hrow[(size_t)s5 * 64 + lane];
        unsigned u6 = hrow[(size_t)s6 * 64 + lane];
        unsigned u7 = hrow[(size_t)s7 * 64 + lane];
        ax += lo16(u0) + lo16(u1) + lo16(u2) + lo16(u3)
            + lo16(u4) + lo16(u5) + lo16(u6) + lo16(u7);
        ay += hi16(u0) + hi16(u1) + hi16(u2) + hi16(u3)
            + hi16(u4) + hi16(u5) + hi16(u6) + hi16(u7);
    }
    for (; i < c; ++i) {
        int s = csr[start + i];
        unsigned us = hrow[(size_t)s * 64 + lane];
        ax += lo16(us);
        ay += hi16(us);
    }
    float2 bb = ((const float2*)b1)[lane];
    float ox = fmaxf(dv * ax + bb.x, 0.f);
    float oy = fmaxf(dv * ay + bb.y, 0.f);
    ((unsigned*)h1)[(size_t)v * 64 + lane] =
        (unsigned)f2bf(ox) | ((unsigned)f2bf(oy) << 16);
}

// ---------------- GEMM2: h1[M,128]bf16 @ W2[128,32]fp32 -> h2s[M,32]bf16 (pre-scaled) ----------------
__global__ __launch_bounds__(256) void k_gemm2(const unsigned short* __restrict__ A,
                                               const float* __restrict__ B,
                                               const float* __restrict__ dinv,
                                               unsigned short* __restrict__ C, int M) {
    __shared__ float Bs[HID][NCLS];   // 16 KB
    __shared__ float As[64][HID];     // 32 KB
    const int tid = threadIdx.x;
#pragma unroll
    for (int it = 0; it < 16; ++it) {
        int idx = tid + 256 * it;
        Bs[idx >> 5][idx & 31] = B[idx];
    }
    int rowBase = blockIdx.x * 64;
    const unsigned* A2 = (const unsigned*)A;
#pragma unroll
    for (int it = 0; it < 16; ++it) {
        int idx = tid + 256 * it;
        int r = idx >> 6, c2 = idx & 63;
        int gr = rowBase + r;
        unsigned u = (gr < M) ? A2[(size_t)gr * 64 + c2] : 0u;
        As[r][2 * c2]     = lo16(u);
        As[r][2 * c2 + 1] = hi16(u);
    }
    __syncthreads();
    int col = tid & 31;
    int rg = tid >> 5;
    float acc[8];
#pragma unroll
    for (int i = 0; i < 8; ++i) acc[i] = 0.f;
    for (int k = 0; k < HID; ++k) {
        float b = Bs[k][col];
#pragma unroll
        for (int i = 0; i < 8; ++i) acc[i] += As[rg * 8 + i][k] * b;
    }
#pragma unroll
    for (int i = 0; i < 8; ++i) {
        int gr = rowBase + rg * 8 + i;
        if (gr < M) C[(size_t)gr * NCLS + col] = f2bf(acc[i] * dinv[gr]);
    }
}

// ---------------- agg layer2: quarter-wave per edge (4/wave), unroll x2 = 8 in flight ----------------
__global__ __launch_bounds__(256) void k_agg2(const unsigned short* __restrict__ h2s,
                                              const int* __restrict__ csr,
                                              const int* __restrict__ rs, const int* __restrict__ cnt,
                                              const float* __restrict__ dinv, const float* __restrict__ b2,
                                              float* __restrict__ out, int N) {
    int v = blockIdx.x * 4 + (threadIdx.x >> 6);
    if (v >= N) return;
    int lane = threadIdx.x & 63;
    int q = lane >> 4;       // quarter 0..3
    int l = lane & 15;       // 2 features per lane
    float dv = dinv[v];
    const unsigned* rows = (const unsigned*)h2s;   // 16 uints per row
    float ax = 0.f, ay = 0.f;
    if (q == 0) {
        unsigned u = rows[(size_t)v * 16 + l];   // self (pre-scaled)
        ax = lo16(u); ay = hi16(u);
    }
    int start = rs[v];
    int c = cnt[v];
    int i = q;
    for (; i + 4 < c; i += 8) {
        int s0 = csr[start + i];
        int s1 = csr[start + i + 4];
        unsigned u0 = rows[(size_t)s0 * 16 + l];
        unsigned u1 = rows[(size_t)s1 * 16 + l];
        ax += lo16(u0) + lo16(u1);
        ay += hi16(u0) + hi16(u1);
    }
    for (; i < c; i += 4) {
        int s = csr[start + i];
        unsigned u = rows[(size_t)s * 16 + l];
        ax += lo16(u);
        ay += hi16(u);
    }
    ax += __shfl_xor(ax, 16, 64);
    ax += __shfl_xor(ax, 32, 64);
    ay += __shfl_xor(ay, 16, 64);
    ay += __shfl_xor(ay, 32, 64);
    if (q == 0) {
        float2 bb = ((const float2*)b2)[l];
        float2 o;
        o.x = dv * ax + bb.x;
        o.y = dv * ay + bb.y;
        *((float2*)(out + (size_t)v * NCLS) + l) = o;
    }
}

// ---------------------------------------------------------------------------
extern "C" void kernel_launch(void* const* d_in, const int* in_sizes, int n_in,
                              void* d_out, int out_size, void* d_ws, size_t ws_size,
                              hipStream_t stream) {
    const float* x = (const float*)d_in[0];
    const int* edge_index = (const int*)d_in[1];
    const float* W1 = (const float*)d_in[2];
    const float* b1 = (const float*)d_in[3];
    const float* W2 = (const float*)d_in[4];
    const float* b2 = (const float*)d_in[5];
    float* out = (float*)d_out;

    const int N = in_sizes[0] / IN_F;       // 100000
    const int E = in_sizes[1] / 2;          // 1600000
    const int* e_src = edge_index;
    const int* e_dst = edge_index + E;

    char* ws = (char*)d_ws;
    size_t off = 0;
    auto alloc = [&](size_t bytes) -> char* {
        char* p = ws + off;
        off += (bytes + 255) & ~(size_t)255;
        return p;
    };
    int* deg             = (int*)alloc((size_t)N * 4);
    float* dinv          = (float*)alloc((size_t)N * 4);
    int* rs              = (int*)alloc((size_t)N * 4);
    int* cursor          = (int*)alloc((size_t)N * 4);
    int* bsum            = (int*)alloc(1024 * 4);
    int* csr             = (int*)alloc((size_t)E * 4);
    unsigned short* W1T  = (unsigned short*)alloc((size_t)HID * IN_F * 2);
    unsigned short* hs   = (unsigned short*)alloc((size_t)N * HID * 2);   // pre-scaled h, bf16
    unsigned short* h1   = (unsigned short*)alloc((size_t)N * HID * 2);
    unsigned short* h2s  = (unsigned short*)alloc((size_t)N * NCLS * 2);  // pre-scaled h2, bf16

    const int nbE = (E + 255) / 256;
    const int nbN = (N + 255) / 256;
    const int nbScan = (N + 2047) / 2048;
    const int nbNode = (N + 3) / 4;

    hipMemsetAsync(deg, 0, (size_t)N * 4, stream);
    k_hist<<<nbE, 256, 0, stream>>>(e_dst, deg, E);
    k_dinv<<<nbN, 256, 0, stream>>>(deg, dinv, N);
    k_scan1<<<nbScan, 256, 0, stream>>>(deg, rs, bsum, N);
    k_scan2<<<1, 64, 0, stream>>>(bsum, nbScan);
    k_scan3<<<nbN, 256, 0, stream>>>(rs, bsum, cursor, N);
    k_scatter<<<nbE, 256, 0, stream>>>(e_src, e_dst, cursor, csr, E);
    k_prep<<<(HID * IN_F) / 256, 256, 0, stream>>>(W1, W1T);

    k_gemm1<<<(N + 127) / 128, 256, 0, stream>>>(x, W1T, dinv, hs, N);
    k_agg1<<<nbNode, 256, 0, stream>>>(hs, csr, rs, deg, dinv, b1, h1, N);
    k_gemm2<<<(N + 63) / 64, 256, 0, stream>>>(h1, W2, dinv, h2s, N);
    k_agg2<<<nbNode, 256, 0, stream>>>(h2s, csr, rs, deg, dinv, b2, out, N);
}